// Round 8
// baseline (534.525 us; speedup 1.0000x reference)
//
#include <hip/hip_runtime.h>
#include <hip/hip_bf16.h>

#define NN 50000
#define NE 800000
#define HH 128

typedef short s16x8 __attribute__((ext_vector_type(8)));
typedef float f32x4 __attribute__((ext_vector_type(4)));
typedef unsigned int u32x4 __attribute__((ext_vector_type(4)));
typedef __bf16 bf16x2 __attribute__((ext_vector_type(2)));

__device__ __forceinline__ float u2f(unsigned int v) {
    float f;
    __builtin_memcpy(&f, &v, 4);
    return f;
}
__device__ __forceinline__ float bf2f(unsigned short u) {
    return u2f(((unsigned int)u) << 16);
}
__device__ __forceinline__ unsigned short f2bf_sw(float f) {
    unsigned int x;
    __builtin_memcpy(&x, &f, 4);
    unsigned int r = (x + 0x7fffu + ((x >> 16) & 1u)) >> 16;
    return (unsigned short)r;
}
__device__ __forceinline__ unsigned int f2bf_pk(float a, float b) {
#if __has_builtin(__builtin_amdgcn_cvt_pk_bf16_f32)
    bf16x2 p = __builtin_amdgcn_cvt_pk_bf16_f32(a, b);
    unsigned int u;
    __builtin_memcpy(&u, &p, 4);
    return u;
#else
    return (unsigned int)f2bf_sw(a) | ((unsigned int)f2bf_sw(b) << 16);
#endif
}
__device__ __forceinline__ unsigned short f2bf(float a) {
#if __has_builtin(__builtin_amdgcn_cvt_pk_bf16_f32)
    return (unsigned short)(f2bf_pk(a, a) & 0xffffu);
#else
    return f2bf_sw(a);
#endif
}
__device__ __forceinline__ float silu(float v) {
    return v * __builtin_amdgcn_rcpf(1.f + __expf(-v));
}

// ---- fused prep: all weight transposes + edge-row count ----
// regions: [0,32768) PWT | [32768,49152) W2T | [49152,65536) Wc1T
//          [65536,98304) Wn1T | [98304,114688) Wn2T | [114688,114688+NE) count
__global__ void prep_kernel(
    const float* __restrict__ W_e1, const float* __restrict__ W_e2,
    const float* __restrict__ W_c1, const float* __restrict__ W_n1,
    const float* __restrict__ W_n2, const int* __restrict__ eidx,
    unsigned short* __restrict__ PWT, unsigned short* __restrict__ W2T,
    unsigned short* __restrict__ Wc1T, unsigned short* __restrict__ Wn1T,
    unsigned short* __restrict__ Wn2T, int* __restrict__ counts) {
    int idx = blockIdx.x * 256 + threadIdx.x;
    if (idx < 32768) {
        int cp = idx >> 7, k = idx & 127;
        int srow = (cp < 128) ? k : (128 + k);
        PWT[idx] = f2bf(W_e1[srow * 128 + (cp & 127)]);
    } else if (idx < 49152) {
        int i = idx - 32768, n = i >> 7, k = i & 127;
        W2T[i] = f2bf(W_e2[k * 128 + n]);
    } else if (idx < 65536) {
        int i = idx - 49152, n = i >> 7, k = i & 127;
        Wc1T[i] = f2bf(W_c1[k * 128 + n]);
    } else if (idx < 98304) {
        int i = idx - 65536, n = i >> 8, k = i & 255;
        Wn1T[i] = f2bf(W_n1[k * 128 + n]);
    } else if (idx < 114688) {
        int i = idx - 98304, n = i >> 7, k = i & 127;
        Wn2T[i] = f2bf(W_n2[k * 128 + n]);
    } else if (idx < 114688 + NE) {
        int e = idx - 114688;
        int r = eidx[e];
        r = r < 0 ? 0 : (r >= NN ? NN - 1 : r);
        atomicAdd(&counts[r], 1);
    }
}

// ---- single-block exclusive scan of counts -> offsets ----
__global__ void k_scan(const int* __restrict__ counts, int* __restrict__ offsets) {
    __shared__ int sm[1024];
    int t = threadIdx.x;
    int base = t * 49;
    int sum = 0;
    for (int i = 0; i < 49; i++) {
        int idx = base + i;
        if (idx < NN) sum += counts[idx];
    }
    sm[t] = sum;
    __syncthreads();
    for (int d = 1; d < 1024; d <<= 1) {
        int add = (t >= d) ? sm[t - d] : 0;
        __syncthreads();
        sm[t] += add;
        __syncthreads();
    }
    int acc = sm[t] - sum;  // exclusive base for this thread
    for (int i = 0; i < 49; i++) {
        int idx = base + i;
        if (idx < NN) {
            offsets[idx] = acc;
            acc += counts[idx];
        }
    }
}

// ---- sort edges into CSR slot order; pack (r,c) u16 pair ----
__global__ void k_fill(const int* __restrict__ eidx, const int* __restrict__ offsets,
                       int* __restrict__ cursor, unsigned int* __restrict__ rc) {
    int e = blockIdx.x * 256 + threadIdx.x;
    if (e >= NE) return;
    int r = eidx[e];
    int c = eidx[NE + e];
    r = r < 0 ? 0 : (r >= NN ? NN - 1 : r);
    c = c < 0 ? 0 : (c >= NN ? NN - 1 : c);
    int slot = offsets[r] + atomicAdd(&cursor[r], 1);
    rc[slot] = (unsigned int)r | ((unsigned int)c << 16);
}

// ---- P-GEMM: P1 = bf16(h)@W_top + b1 (folded), P2 = bf16(h)@W_bot ----
__global__ __launch_bounds__(256, 4) void pgemm(
    const float* __restrict__ h, const unsigned short* __restrict__ PWT,
    const float* __restrict__ b1,
    unsigned short* __restrict__ P1, unsigned short* __restrict__ P2) {
    __shared__ unsigned short Alds[64 * 136];
    const int tid = threadIdx.x;
    const int n0 = blockIdx.x * 64;

#pragma unroll
    for (int j = 0; j < 4; j++) {
        int idx = tid + j * 256;
        int e = idx >> 4, ch = idx & 15;
        int node = n0 + e;
        if (node >= NN) node = NN - 1;
        const f32x4* p = (const f32x4*)&h[node * 128 + ch * 8];
        f32x4 a = p[0], b = p[1];
        u32x4 s;
        s[0] = f2bf_pk(a[0], a[1]);
        s[1] = f2bf_pk(a[2], a[3]);
        s[2] = f2bf_pk(b[0], b[1]);
        s[3] = f2bf_pk(b[2], b[3]);
        *(u32x4*)&Alds[e * 136 + ch * 8] = s;
    }
    __syncthreads();

    const int lane = tid & 63;
    const int w = tid >> 6;
    const int ln15 = lane & 15;
    const int q8 = (lane >> 4) * 8, q4 = (lane >> 4) * 4;
    const int cbase = w * 64;

    f32x4 acc[4][4];
#pragma unroll
    for (int et = 0; et < 4; et++)
#pragma unroll
        for (int nt = 0; nt < 4; nt++) acc[et][nt] = (f32x4){0.f, 0.f, 0.f, 0.f};
#pragma unroll
    for (int kk = 0; kk < 4; kk++) {
        int k0 = kk * 32 + q8;
        s16x8 a[4], b[4];
#pragma unroll
        for (int et = 0; et < 4; et++)
            a[et] = *(const s16x8*)&Alds[(et * 16 + ln15) * 136 + k0];
#pragma unroll
        for (int nt = 0; nt < 4; nt++)
            b[nt] = *(const s16x8*)&PWT[(cbase + nt * 16 + ln15) * 128 + k0];
#pragma unroll
        for (int et = 0; et < 4; et++)
#pragma unroll
            for (int nt = 0; nt < 4; nt++)
                acc[et][nt] = __builtin_amdgcn_mfma_f32_16x16x32_bf16(
                    a[et], b[nt], acc[et][nt], 0, 0, 0);
    }
#pragma unroll
    for (int nt = 0; nt < 4; nt++) {
        int cp = cbase + nt * 16 + ln15;
        bool top = cp < 128;
        unsigned short* dst = top ? P1 : P2;
        int col = cp & 127;
        float badd = top ? b1[col] : 0.f;
#pragma unroll
        for (int et = 0; et < 4; et++)
#pragma unroll
            for (int r = 0; r < 4; r++) {
                int row = et * 16 + q4 + r;
                int node = n0 + row;
                if (node >= NN) node = NN - 1;
                dst[node * 128 + col] = f2bf(acc[et][nt][r] + badd);
            }
    }
}

// ---- edge kernel: 128 CSR-sorted edge slots per block, 512 threads ----
__global__ __launch_bounds__(512, 8) void edge_kernel(
    const unsigned short* __restrict__ P1, const unsigned short* __restrict__ P2,
    const float* __restrict__ x, const unsigned int* __restrict__ rc,
    const float* __restrict__ W1full,
    const unsigned short* __restrict__ W2T, const float* __restrict__ b2,
    const unsigned short* __restrict__ Wc1T, const float* __restrict__ bc1,
    const float* __restrict__ wc2,
    float* __restrict__ m_i, float* __restrict__ x_acc) {
    __shared__ unsigned short mid1[128 * 132];  // silu(e1) bf16; later m_ij
    __shared__ float wls[128];
    __shared__ float rad[128], ndx[128], ndy[128], ndz[128], fsum[128];
    __shared__ int rowA[128], colA[128];

    const int tid = threadIdx.x;
    const int e0 = blockIdx.x * 128;

    if (tid < 128) {
        unsigned int pk = rc[e0 + tid];
        int r = pk & 0xffff, c = pk >> 16;
        rowA[tid] = r; colA[tid] = c;
        float dx = x[r * 3 + 0] - x[c * 3 + 0];
        float dy = x[r * 3 + 1] - x[c * 3 + 1];
        float dz = x[r * 3 + 2] - x[c * 3 + 2];
        float d2 = dx * dx + dy * dy + dz * dz;
        float dist = sqrtf(d2);
        float inv = __builtin_amdgcn_rcpf(dist + 1e-8f);
        rad[tid] = d2;
        ndx[tid] = dx * inv; ndy[tid] = dy * inv; ndz[tid] = dz * inv;
        fsum[tid] = 0.f;
    } else if (tid < 256) {
        int c = tid - 128;
        wls[c] = W1full[256 * 128 + c];
    }
    __syncthreads();

    // stage mid1 = silu(P1[row](+b1) + P2[col] + rad*wl)
#pragma unroll
    for (int j = 0; j < 4; j++) {
        int idx = tid + j * 512;
        int e = idx >> 4, ch = idx & 15;
        int r = rowA[e], c = colA[e];
        u32x4 p1 = *(const u32x4*)&P1[(size_t)r * 128 + ch * 8];
        u32x4 p2 = *(const u32x4*)&P2[(size_t)c * 128 + ch * 8];
        float rd = rad[e];
        u32x4 s;
#pragma unroll
        for (int t = 0; t < 4; t++) {
            int col = ch * 8 + t * 2;
            float a0 = u2f(p1[t] << 16), a1 = u2f(p1[t] & 0xffff0000u);
            float c0 = u2f(p2[t] << 16), c1 = u2f(p2[t] & 0xffff0000u);
            float v0 = a0 + c0 + rd * wls[col];
            float v1 = a1 + c1 + rd * wls[col + 1];
            s[t] = f2bf_pk(silu(v0), silu(v1));
        }
        *(u32x4*)&mid1[e * 132 + ch * 8] = s;
    }
    __syncthreads();

    const int lane = tid & 63;
    const int w = tid >> 6;       // 0..7
    const int ln15 = lane & 15;
    const int q8 = (lane >> 4) * 8, q4 = (lane >> 4) * 4;
    const int nbase = (w & 3) * 32;  // output col base
    const int rb = (w >> 2) * 64;    // row (edge) base for this wave

    f32x4 acc[4][2];

    // ---- layer e2: silu([128x128]@W2 + b2) = m_ij
#pragma unroll
    for (int et = 0; et < 4; et++)
#pragma unroll
        for (int nt = 0; nt < 2; nt++) acc[et][nt] = (f32x4){0.f, 0.f, 0.f, 0.f};
#pragma unroll
    for (int kk = 0; kk < 4; kk++) {
        int k0 = kk * 32 + q8;
        s16x8 a[4], b[2];
#pragma unroll
        for (int et = 0; et < 4; et++)
            a[et] = *(const s16x8*)&mid1[(rb + et * 16 + ln15) * 132 + k0];
#pragma unroll
        for (int nt = 0; nt < 2; nt++)
            b[nt] = *(const s16x8*)&W2T[(nbase + nt * 16 + ln15) * 128 + k0];
#pragma unroll
        for (int et = 0; et < 4; et++)
#pragma unroll
            for (int nt = 0; nt < 2; nt++)
                acc[et][nt] = __builtin_amdgcn_mfma_f32_16x16x32_bf16(
                    a[et], b[nt], acc[et][nt], 0, 0, 0);
    }
    __syncthreads();  // all mid1 reads done; reuse as mid2
    unsigned short* mid2 = mid1;
#pragma unroll
    for (int nt = 0; nt < 2; nt++) {
        int col = nbase + nt * 16 + ln15;
        float bias = b2[col];
#pragma unroll
        for (int et = 0; et < 4; et++)
#pragma unroll
            for (int r = 0; r < 4; r++) {
                int row = rb + et * 16 + q4 + r;
                mid2[row * 132 + col] = f2bf(silu(acc[et][nt][r] + bias));
            }
    }
    __syncthreads();

    // ---- coord layer: c1 = silu(m_ij @ Wc1 + bc1)
#pragma unroll
    for (int et = 0; et < 4; et++)
#pragma unroll
        for (int nt = 0; nt < 2; nt++) acc[et][nt] = (f32x4){0.f, 0.f, 0.f, 0.f};
#pragma unroll
    for (int kk = 0; kk < 4; kk++) {
        int k0 = kk * 32 + q8;
        s16x8 a[4], b[2];
#pragma unroll
        for (int et = 0; et < 4; et++)
            a[et] = *(const s16x8*)&mid2[(rb + et * 16 + ln15) * 132 + k0];
#pragma unroll
        for (int nt = 0; nt < 2; nt++)
            b[nt] = *(const s16x8*)&Wc1T[(nbase + nt * 16 + ln15) * 128 + k0];
#pragma unroll
        for (int et = 0; et < 4; et++)
#pragma unroll
            for (int nt = 0; nt < 2; nt++)
                acc[et][nt] = __builtin_amdgcn_mfma_f32_16x16x32_bf16(
                    a[et], b[nt], acc[et][nt], 0, 0, 0);
    }

    // ---- m_i segment-reduce from mid2 (u32 col-pairs; sorted rows) ----
    {
        int cp2 = (tid & 63) * 2;          // two adjacent cols
        int g = tid >> 6;                  // row group 0..7
        int r0 = g * 16;
        float a0 = 0.f, a1 = 0.f;
        int cur = rowA[r0];
        for (int row = r0; row < r0 + 16; row++) {
            int rn = rowA[row];
            if (rn != cur) {
                atomicAdd(&m_i[(size_t)cur * 128 + cp2], a0);
                atomicAdd(&m_i[(size_t)cur * 128 + cp2 + 1], a1);
                a0 = 0.f; a1 = 0.f;
                cur = rn;
            }
            unsigned int v = *(const unsigned int*)&mid2[row * 132 + cp2];
            a0 += u2f(v << 16);
            a1 += u2f(v & 0xffff0000u);
        }
        atomicAdd(&m_i[(size_t)cur * 128 + cp2], a0);
        atomicAdd(&m_i[(size_t)cur * 128 + cp2 + 1], a1);
    }

    // ---- coord epilogue: fs = tanh(c1 . wc2) * 0.1
    {
        float part[4][4];
#pragma unroll
        for (int et = 0; et < 4; et++)
#pragma unroll
            for (int r = 0; r < 4; r++) part[et][r] = 0.f;
#pragma unroll
        for (int nt = 0; nt < 2; nt++) {
            int col = nbase + nt * 16 + ln15;
            float bias = bc1[col];
            float w2 = wc2[col];
#pragma unroll
            for (int et = 0; et < 4; et++)
#pragma unroll
                for (int r = 0; r < 4; r++)
                    part[et][r] += silu(acc[et][nt][r] + bias) * w2;
        }
#pragma unroll
        for (int et = 0; et < 4; et++)
#pragma unroll
            for (int r = 0; r < 4; r++) {
                float p = part[et][r];
                p += __shfl_xor(p, 8, 16);
                p += __shfl_xor(p, 4, 16);
                p += __shfl_xor(p, 2, 16);
                p += __shfl_xor(p, 1, 16);
                if (ln15 == 0) atomicAdd(&fsum[rb + et * 16 + q4 + r], p);
            }
    }
    __syncthreads();
    if (tid < 128) {
        float fs = tanhf(fsum[tid]) * 0.1f;
        ndx[tid] *= fs; ndy[tid] *= fs; ndz[tid] *= fs;
    }
    __syncthreads();
    if (tid < 128) {
        bool head = (tid == 0) || (rowA[tid] != rowA[tid - 1]);
        if (head) {
            int rn = rowA[tid];
            float ax = 0.f, ay = 0.f, az = 0.f;
            for (int j = tid; j < 128 && rowA[j] == rn; j++) {
                ax += ndx[j]; ay += ndy[j]; az += ndz[j];
            }
            atomicAdd(&x_acc[rn * 3 + 0], ax);
            atomicAdd(&x_acc[rn * 3 + 1], ay);
            atomicAdd(&x_acc[rn * 3 + 2], az);
        }
    }
}

// ---- node kernel: 64 nodes per block + fused x update ----
__global__ __launch_bounds__(256, 4) void node_kernel(
    const float* __restrict__ h, const float* __restrict__ m_i,
    const float* __restrict__ x, const float* __restrict__ x_acc,
    const unsigned short* __restrict__ Wn1T, const float* __restrict__ bn1,
    const unsigned short* __restrict__ Wn2T, const float* __restrict__ bn2,
    const float* __restrict__ ln_g, const float* __restrict__ ln_b,
    float* __restrict__ out_h, float* __restrict__ out_x) {
    __shared__ unsigned short Alds[64 * 264];
    unsigned short* mid1 = Alds;
    float* tile = (float*)Alds;

    const int tid = threadIdx.x;
    const int n0 = blockIdx.x * 64;

    // fused x update for this block's 64 nodes (192 floats)
    if (tid < 192) {
        int i = n0 * 3 + tid;
        if (i < NN * 3) out_x[i] = x[i] + x_acc[i];
    }

    // stage A = [bf16(h) | bf16(m_i)]
#pragma unroll
    for (int i = 0; i < 8; i++) {
        int idx = tid + i * 256;
        int hr = idx >> 4, ch = idx & 15;
        int e = hr >> 1, half = hr & 1;
        int node = n0 + e;
        if (node >= NN) node = NN - 1;
        const float* src = half ? &m_i[(size_t)node * 128 + ch * 8]
                                : &h[(size_t)node * 128 + ch * 8];
        const f32x4* sp = (const f32x4*)src;
        f32x4 f0 = sp[0], f1 = sp[1];
        u32x4 s;
        s[0] = f2bf_pk(f0[0], f0[1]);
        s[1] = f2bf_pk(f0[2], f0[3]);
        s[2] = f2bf_pk(f1[0], f1[1]);
        s[3] = f2bf_pk(f1[2], f1[3]);
        *(u32x4*)&Alds[e * 264 + half * 128 + ch * 8] = s;
    }
    __syncthreads();

    const int lane = tid & 63;
    const int w = tid >> 6;
    const int ln15 = lane & 15;
    const int q8 = (lane >> 4) * 8, q4 = (lane >> 4) * 4;
    const int nbase = w * 32;

    f32x4 acc[4][2];

    // ---- layer n1: K=256
#pragma unroll
    for (int et = 0; et < 4; et++)
#pragma unroll
        for (int nt = 0; nt < 2; nt++) acc[et][nt] = (f32x4){0.f, 0.f, 0.f, 0.f};
#pragma unroll
    for (int kk = 0; kk < 8; kk++) {
        int k0 = kk * 32 + q8;
        s16x8 a[4], b[2];
#pragma unroll
        for (int et = 0; et < 4; et++)
            a[et] = *(const s16x8*)&Alds[(et * 16 + ln15) * 264 + k0];
#pragma unroll
        for (int nt = 0; nt < 2; nt++)
            b[nt] = *(const s16x8*)&Wn1T[(nbase + nt * 16 + ln15) * 256 + k0];
#pragma unroll
        for (int et = 0; et < 4; et++)
#pragma unroll
            for (int nt = 0; nt < 2; nt++)
                acc[et][nt] = __builtin_amdgcn_mfma_f32_16x16x32_bf16(
                    a[et], b[nt], acc[et][nt], 0, 0, 0);
    }
    __syncthreads();  // A dead; mid1 overwrites
#pragma unroll
    for (int nt = 0; nt < 2; nt++) {
        int col = nbase + nt * 16 + ln15;
        float bias = bn1[col];
#pragma unroll
        for (int et = 0; et < 4; et++)
#pragma unroll
            for (int r = 0; r < 4; r++) {
                int row = et * 16 + q4 + r;
                mid1[row * 132 + col] = f2bf(silu(acc[et][nt][r] + bias));
            }
    }
    __syncthreads();

    // ---- layer n2: K=128
#pragma unroll
    for (int et = 0; et < 4; et++)
#pragma unroll
        for (int nt = 0; nt < 2; nt++) acc[et][nt] = (f32x4){0.f, 0.f, 0.f, 0.f};
#pragma unroll
    for (int kk = 0; kk < 4; kk++) {
        int k0 = kk * 32 + q8;
        s16x8 a[4], b[2];
#pragma unroll
        for (int et = 0; et < 4; et++)
            a[et] = *(const s16x8*)&mid1[(et * 16 + ln15) * 132 + k0];
#pragma unroll
        for (int nt = 0; nt < 2; nt++)
            b[nt] = *(const s16x8*)&Wn2T[(nbase + nt * 16 + ln15) * 128 + k0];
#pragma unroll
        for (int et = 0; et < 4; et++)
#pragma unroll
            for (int nt = 0; nt < 2; nt++)
                acc[et][nt] = __builtin_amdgcn_mfma_f32_16x16x32_bf16(
                    a[et], b[nt], acc[et][nt], 0, 0, 0);
    }
    __syncthreads();  // mid1 dead; f32 tile overwrites
#pragma unroll
    for (int nt = 0; nt < 2; nt++) {
        int col = nbase + nt * 16 + ln15;
        float bias = bn2[col];
#pragma unroll
        for (int et = 0; et < 4; et++)
#pragma unroll
            for (int r = 0; r < 4; r++) {
                int row = et * 16 + q4 + r;
                int node = n0 + row;
                int nclamp = node >= NN ? NN - 1 : node;
                float v = acc[et][nt][r] + bias + h[(size_t)nclamp * 128 + col];
                tile[row * 132 + col] = v;
            }
    }
    __syncthreads();

    // ---- LayerNorm: 4 threads/row, interleaved cols
    {
        int row = tid >> 2;
        int q = tid & 3;
        float s = 0.f, s2 = 0.f;
#pragma unroll
        for (int c = 0; c < 32; c++) {
            float v = tile[row * 132 + q + c * 4];
            s += v; s2 += v * v;
        }
        s += __shfl_xor(s, 1, 4);  s2 += __shfl_xor(s2, 1, 4);
        s += __shfl_xor(s, 2, 4);  s2 += __shfl_xor(s2, 2, 4);
        float mean = s * (1.f / 128.f);
        float var = s2 * (1.f / 128.f) - mean * mean;
        float rs = rsqrtf(var + 1e-5f);
        int node = n0 + row;
        if (node < NN) {
#pragma unroll
            for (int c = 0; c < 32; c++) {
                int col = q + c * 4;
                float v = (tile[row * 132 + col] - mean) * rs * ln_g[col] + ln_b[col];
                out_h[(size_t)node * 128 + col] = v;
            }
        }
    }
}

extern "C" void kernel_launch(void* const* d_in, const int* in_sizes, int n_in,
                              void* d_out, int out_size, void* d_ws, size_t ws_size,
                              hipStream_t stream) {
    const float* h    = (const float*)d_in[0];
    const float* x    = (const float*)d_in[1];
    const int* eidx   = (const int*)d_in[2];
    const float* W_e1 = (const float*)d_in[3];
    const float* b_e1 = (const float*)d_in[4];
    const float* W_e2 = (const float*)d_in[5];
    const float* b_e2 = (const float*)d_in[6];
    const float* W_c1 = (const float*)d_in[7];
    const float* b_c1 = (const float*)d_in[8];
    const float* W_c2 = (const float*)d_in[9];
    const float* W_n1 = (const float*)d_in[10];
    const float* b_n1 = (const float*)d_in[11];
    const float* W_n2 = (const float*)d_in[12];
    const float* b_n2 = (const float*)d_in[13];
    const float* ln_g = (const float*)d_in[14];
    const float* ln_b = (const float*)d_in[15];

    float* out_h = (float*)d_out;
    float* out_x = out_h + NN * HH;

    char* ws = (char*)d_ws;
    float* m_i    = (float*)ws;                       // 25,600,000 (zero)
    float* x_acc  = (float*)(ws + 25600000);          //    600,000 (zero)
    int* counts   = (int*)(ws + 26200000);            //    200,000 (zero)
    int* cursor   = (int*)(ws + 26400000);            //    200,000 (zero)
    int* offsets  = (int*)(ws + 26600000);            //    200,000
    unsigned int* rc = (unsigned int*)(ws + 26802048);       //  3,200,000
    unsigned short* P1  = (unsigned short*)(ws + 30002048);  // 12,800,000
    unsigned short* P2  = (unsigned short*)(ws + 42802048);  // 12,800,000
    unsigned short* PWT = (unsigned short*)(ws + 55602048);  //     65,536
    unsigned short* W2T  = (unsigned short*)(ws + 55667584); //     32,768
    unsigned short* Wc1T = (unsigned short*)(ws + 55700352); //     32,768
    unsigned short* Wn1T = (unsigned short*)(ws + 55733120); //     65,536
    unsigned short* Wn2T = (unsigned short*)(ws + 55798656); //     32,768

    hipMemsetAsync(ws, 0, 26800000, stream);  // m_i + x_acc + counts + cursor

    prep_kernel<<<(114688 + NE + 255) / 256, 256, 0, stream>>>(
        W_e1, W_e2, W_c1, W_n1, W_n2, eidx, PWT, W2T, Wc1T, Wn1T, Wn2T, counts);
    k_scan<<<1, 1024, 0, stream>>>(counts, offsets);
    k_fill<<<(NE + 255) / 256, 256, 0, stream>>>(eidx, offsets, cursor, rc);
    pgemm<<<(NN + 63) / 64, 256, 0, stream>>>(h, PWT, b_e1, P1, P2);

    edge_kernel<<<NE / 128, 512, 0, stream>>>(P1, P2, x, rc, W_e1, W2T, b_e2,
                                              Wc1T, b_c1, W_c2, m_i, x_acc);
    node_kernel<<<(NN + 63) / 64, 256, 0, stream>>>(
        h, m_i, x, x_acc, Wn1T, b_n1, Wn2T, b_n2, ln_g, ln_b, out_h, out_x);
}

// Round 9
// 433.927 us; speedup vs baseline: 1.2318x; 1.2318x over previous
//
#include <hip/hip_runtime.h>
#include <hip/hip_bf16.h>

#define NN 50000
#define NE 800000
#define HH 128
#define SCAN_NB 196  // ceil(50000/256)

typedef short s16x8 __attribute__((ext_vector_type(8)));
typedef float f32x4 __attribute__((ext_vector_type(4)));
typedef unsigned int u32x4 __attribute__((ext_vector_type(4)));
typedef __bf16 bf16x2 __attribute__((ext_vector_type(2)));

__device__ __forceinline__ float u2f(unsigned int v) {
    float f;
    __builtin_memcpy(&f, &v, 4);
    return f;
}
__device__ __forceinline__ float bf2f(unsigned short u) {
    return u2f(((unsigned int)u) << 16);
}
__device__ __forceinline__ unsigned short f2bf_sw(float f) {
    unsigned int x;
    __builtin_memcpy(&x, &f, 4);
    unsigned int r = (x + 0x7fffu + ((x >> 16) & 1u)) >> 16;
    return (unsigned short)r;
}
__device__ __forceinline__ unsigned int f2bf_pk(float a, float b) {
#if __has_builtin(__builtin_amdgcn_cvt_pk_bf16_f32)
    bf16x2 p = __builtin_amdgcn_cvt_pk_bf16_f32(a, b);
    unsigned int u;
    __builtin_memcpy(&u, &p, 4);
    return u;
#else
    return (unsigned int)f2bf_sw(a) | ((unsigned int)f2bf_sw(b) << 16);
#endif
}
__device__ __forceinline__ unsigned short f2bf(float a) {
#if __has_builtin(__builtin_amdgcn_cvt_pk_bf16_f32)
    return (unsigned short)(f2bf_pk(a, a) & 0xffffu);
#else
    return f2bf_sw(a);
#endif
}
__device__ __forceinline__ float silu(float v) {
    return v * __builtin_amdgcn_rcpf(1.f + __expf(-v));
}

// ---- fused prep: all weight transposes + edge-row count ----
__global__ void prep_kernel(
    const float* __restrict__ W_e1, const float* __restrict__ W_e2,
    const float* __restrict__ W_c1, const float* __restrict__ W_n1,
    const float* __restrict__ W_n2, const int* __restrict__ eidx,
    unsigned short* __restrict__ PWT, unsigned short* __restrict__ W2T,
    unsigned short* __restrict__ Wc1T, unsigned short* __restrict__ Wn1T,
    unsigned short* __restrict__ Wn2T, int* __restrict__ counts) {
    int idx = blockIdx.x * 256 + threadIdx.x;
    if (idx < 32768) {
        int cp = idx >> 7, k = idx & 127;
        int srow = (cp < 128) ? k : (128 + k);
        PWT[idx] = f2bf(W_e1[srow * 128 + (cp & 127)]);
    } else if (idx < 49152) {
        int i = idx - 32768, n = i >> 7, k = i & 127;
        W2T[i] = f2bf(W_e2[k * 128 + n]);
    } else if (idx < 65536) {
        int i = idx - 49152, n = i >> 7, k = i & 127;
        Wc1T[i] = f2bf(W_c1[k * 128 + n]);
    } else if (idx < 98304) {
        int i = idx - 65536, n = i >> 8, k = i & 255;
        Wn1T[i] = f2bf(W_n1[k * 128 + n]);
    } else if (idx < 114688) {
        int i = idx - 98304, n = i >> 7, k = i & 127;
        Wn2T[i] = f2bf(W_n2[k * 128 + n]);
    } else if (idx < 114688 + NE) {
        int e = idx - 114688;
        int r = eidx[e];
        r = r < 0 ? 0 : (r >= NN ? NN - 1 : r);
        atomicAdd(&counts[r], 1);
    }
}

// ---- coalesced hierarchical scan (3 tiny kernels) ----
__global__ void k_partial(const int* __restrict__ counts, int* __restrict__ partials) {
    __shared__ int sm[256];
    int idx = blockIdx.x * 256 + threadIdx.x;
    sm[threadIdx.x] = idx < NN ? counts[idx] : 0;
    __syncthreads();
    for (int s = 128; s > 0; s >>= 1) {
        if (threadIdx.x < s) sm[threadIdx.x] += sm[threadIdx.x + s];
        __syncthreads();
    }
    if (threadIdx.x == 0) partials[blockIdx.x] = sm[0];
}
__global__ void k_scanp(const int* __restrict__ partials, int* __restrict__ scanp) {
    __shared__ int sm[256];
    int t = threadIdx.x;
    int v = t < SCAN_NB ? partials[t] : 0;
    sm[t] = v;
    __syncthreads();
    for (int d = 1; d < 256; d <<= 1) {
        int add = t >= d ? sm[t - d] : 0;
        __syncthreads();
        sm[t] += add;
        __syncthreads();
    }
    scanp[t] = sm[t] - v;  // exclusive
}
__global__ void k_offsets(const int* __restrict__ counts, const int* __restrict__ scanp,
                          int* __restrict__ offsets) {
    __shared__ int sm[256];
    int t = threadIdx.x, idx = blockIdx.x * 256 + t;
    int v = idx < NN ? counts[idx] : 0;
    sm[t] = v;
    __syncthreads();
    for (int d = 1; d < 256; d <<= 1) {
        int add = t >= d ? sm[t - d] : 0;
        __syncthreads();
        sm[t] += add;
        __syncthreads();
    }
    if (idx < NN) offsets[idx] = sm[t] - v + scanp[blockIdx.x];
}

// ---- sort edges into CSR slot order; pack (r,c) u16 pair ----
__global__ void k_fill(const int* __restrict__ eidx, const int* __restrict__ offsets,
                       int* __restrict__ cursor, unsigned int* __restrict__ rc) {
    int e = blockIdx.x * 256 + threadIdx.x;
    if (e >= NE) return;
    int r = eidx[e];
    int c = eidx[NE + e];
    r = r < 0 ? 0 : (r >= NN ? NN - 1 : r);
    c = c < 0 ? 0 : (c >= NN ? NN - 1 : c);
    int slot = offsets[r] + atomicAdd(&cursor[r], 1);
    rc[slot] = (unsigned int)r | ((unsigned int)c << 16);
}

// ---- P-GEMM: P1 = bf16(h)@W_top + b1 (folded), P2 = bf16(h)@W_bot; f32 out ----
__global__ __launch_bounds__(256, 4) void pgemm(
    const float* __restrict__ h, const unsigned short* __restrict__ PWT,
    const float* __restrict__ b1,
    float* __restrict__ P1, float* __restrict__ P2) {
    __shared__ unsigned short Alds[64 * 136];
    const int tid = threadIdx.x;
    const int n0 = blockIdx.x * 64;

#pragma unroll
    for (int j = 0; j < 4; j++) {
        int idx = tid + j * 256;
        int e = idx >> 4, ch = idx & 15;
        int node = n0 + e;
        if (node >= NN) node = NN - 1;
        const f32x4* p = (const f32x4*)&h[node * 128 + ch * 8];
        f32x4 a = p[0], b = p[1];
        u32x4 s;
        s[0] = f2bf_pk(a[0], a[1]);
        s[1] = f2bf_pk(a[2], a[3]);
        s[2] = f2bf_pk(b[0], b[1]);
        s[3] = f2bf_pk(b[2], b[3]);
        *(u32x4*)&Alds[e * 136 + ch * 8] = s;
    }
    __syncthreads();

    const int lane = tid & 63;
    const int w = tid >> 6;
    const int ln15 = lane & 15;
    const int q8 = (lane >> 4) * 8, q4 = (lane >> 4) * 4;
    const int cbase = w * 64;

    f32x4 acc[4][4];
#pragma unroll
    for (int et = 0; et < 4; et++)
#pragma unroll
        for (int nt = 0; nt < 4; nt++) acc[et][nt] = (f32x4){0.f, 0.f, 0.f, 0.f};
#pragma unroll
    for (int kk = 0; kk < 4; kk++) {
        int k0 = kk * 32 + q8;
        s16x8 a[4], b[4];
#pragma unroll
        for (int et = 0; et < 4; et++)
            a[et] = *(const s16x8*)&Alds[(et * 16 + ln15) * 136 + k0];
#pragma unroll
        for (int nt = 0; nt < 4; nt++)
            b[nt] = *(const s16x8*)&PWT[(cbase + nt * 16 + ln15) * 128 + k0];
#pragma unroll
        for (int et = 0; et < 4; et++)
#pragma unroll
            for (int nt = 0; nt < 4; nt++)
                acc[et][nt] = __builtin_amdgcn_mfma_f32_16x16x32_bf16(
                    a[et], b[nt], acc[et][nt], 0, 0, 0);
    }
#pragma unroll
    for (int nt = 0; nt < 4; nt++) {
        int cp = cbase + nt * 16 + ln15;
        bool top = cp < 128;
        float* dst = top ? P1 : P2;
        int col = cp & 127;
        float badd = top ? b1[col] : 0.f;
#pragma unroll
        for (int et = 0; et < 4; et++)
#pragma unroll
            for (int r = 0; r < 4; r++) {
                int row = et * 16 + q4 + r;
                int node = n0 + row;
                if (node >= NN) node = NN - 1;
                dst[(size_t)node * 128 + col] = acc[et][nt][r] + badd;
            }
    }
}

// ---- edge kernel: 64 CSR-sorted edge slots per block, 256 threads ----
__global__ __launch_bounds__(256, 8) void edge_kernel(
    const float* __restrict__ P1, const float* __restrict__ P2,
    const float* __restrict__ x, const unsigned int* __restrict__ rc,
    const float* __restrict__ W1full,
    const unsigned short* __restrict__ W2T, const float* __restrict__ b2,
    const unsigned short* __restrict__ Wc1T, const float* __restrict__ bc1,
    const float* __restrict__ wc2,
    float* __restrict__ m_i, float* __restrict__ x_acc) {
    __shared__ unsigned short mid1[64 * 132];  // silu(e1) bf16; later m_ij
    __shared__ float wls[128];
    __shared__ float rad[64], ndx[64], ndy[64], ndz[64], fsum[64];
    __shared__ int rowA[64], colA[64];

    const int tid = threadIdx.x;
    const int e0 = blockIdx.x * 64;

    if (tid < 64) {
        unsigned int pk = rc[e0 + tid];
        int r = pk & 0xffff, c = pk >> 16;
        rowA[tid] = r; colA[tid] = c;
        float dx = x[r * 3 + 0] - x[c * 3 + 0];
        float dy = x[r * 3 + 1] - x[c * 3 + 1];
        float dz = x[r * 3 + 2] - x[c * 3 + 2];
        float d2 = dx * dx + dy * dy + dz * dz;
        float dist = sqrtf(d2);
        float inv = __builtin_amdgcn_rcpf(dist + 1e-8f);
        rad[tid] = d2;
        ndx[tid] = dx * inv; ndy[tid] = dy * inv; ndz[tid] = dz * inv;
        fsum[tid] = 0.f;
    } else if (tid >= 128 && tid < 256) {
        int c = tid - 128;
        wls[c] = W1full[256 * 128 + c];
    }
    __syncthreads();

    // stage mid1 = silu(P1[row](+b1) + P2[col] + rad*wl) — all-f32 inputs
#pragma unroll
    for (int j = 0; j < 4; j++) {
        int idx = tid + j * 256;
        int e = idx >> 4, ch = idx & 15;
        int r = rowA[e], c = colA[e];
        const f32x4* q1 = (const f32x4*)&P1[(size_t)r * 128 + ch * 8];
        const f32x4* q2 = (const f32x4*)&P2[(size_t)c * 128 + ch * 8];
        f32x4 a0 = q1[0], a1 = q1[1];
        f32x4 c0 = q2[0], c1 = q2[1];
        float rd = rad[e];
        int colb = ch * 8;
        u32x4 s;
#pragma unroll
        for (int t = 0; t < 2; t++) {
            float v0 = a0[t * 2] + c0[t * 2] + rd * wls[colb + t * 2];
            float v1 = a0[t * 2 + 1] + c0[t * 2 + 1] + rd * wls[colb + t * 2 + 1];
            s[t] = f2bf_pk(silu(v0), silu(v1));
        }
#pragma unroll
        for (int t = 0; t < 2; t++) {
            int cc = colb + 4 + t * 2;
            float v0 = a1[t * 2] + c1[t * 2] + rd * wls[cc];
            float v1 = a1[t * 2 + 1] + c1[t * 2 + 1] + rd * wls[cc + 1];
            s[t + 2] = f2bf_pk(silu(v0), silu(v1));
        }
        *(u32x4*)&mid1[e * 132 + ch * 8] = s;
    }
    __syncthreads();

    const int lane = tid & 63;
    const int w = tid >> 6;
    const int ln15 = lane & 15;
    const int q8 = (lane >> 4) * 8, q4 = (lane >> 4) * 4;
    const int nbase = w * 32;

    f32x4 acc[4][2];

    // ---- layer e2: silu([64x128]@W2 + b2) = m_ij
#pragma unroll
    for (int et = 0; et < 4; et++)
#pragma unroll
        for (int nt = 0; nt < 2; nt++) acc[et][nt] = (f32x4){0.f, 0.f, 0.f, 0.f};
#pragma unroll
    for (int kk = 0; kk < 4; kk++) {
        int k0 = kk * 32 + q8;
        s16x8 a[4], b[2];
#pragma unroll
        for (int et = 0; et < 4; et++)
            a[et] = *(const s16x8*)&mid1[(et * 16 + ln15) * 132 + k0];
#pragma unroll
        for (int nt = 0; nt < 2; nt++)
            b[nt] = *(const s16x8*)&W2T[(nbase + nt * 16 + ln15) * 128 + k0];
#pragma unroll
        for (int et = 0; et < 4; et++)
#pragma unroll
            for (int nt = 0; nt < 2; nt++)
                acc[et][nt] = __builtin_amdgcn_mfma_f32_16x16x32_bf16(
                    a[et], b[nt], acc[et][nt], 0, 0, 0);
    }
    __syncthreads();  // all mid1 reads done; reuse as mid2
    unsigned short* mid2 = mid1;
#pragma unroll
    for (int nt = 0; nt < 2; nt++) {
        int col = nbase + nt * 16 + ln15;
        float bias = b2[col];
#pragma unroll
        for (int et = 0; et < 4; et++)
#pragma unroll
            for (int r = 0; r < 4; r++) {
                int row = et * 16 + q4 + r;
                mid2[row * 132 + col] = f2bf(silu(acc[et][nt][r] + bias));
            }
    }
    __syncthreads();

    // ---- coord layer: c1 = silu(m_ij @ Wc1 + bc1)
#pragma unroll
    for (int et = 0; et < 4; et++)
#pragma unroll
        for (int nt = 0; nt < 2; nt++) acc[et][nt] = (f32x4){0.f, 0.f, 0.f, 0.f};
#pragma unroll
    for (int kk = 0; kk < 4; kk++) {
        int k0 = kk * 32 + q8;
        s16x8 a[4], b[2];
#pragma unroll
        for (int et = 0; et < 4; et++)
            a[et] = *(const s16x8*)&mid2[(et * 16 + ln15) * 132 + k0];
#pragma unroll
        for (int nt = 0; nt < 2; nt++)
            b[nt] = *(const s16x8*)&Wc1T[(nbase + nt * 16 + ln15) * 128 + k0];
#pragma unroll
        for (int et = 0; et < 4; et++)
#pragma unroll
            for (int nt = 0; nt < 2; nt++)
                acc[et][nt] = __builtin_amdgcn_mfma_f32_16x16x32_bf16(
                    a[et], b[nt], acc[et][nt], 0, 0, 0);
    }

    // ---- m_i segment-reduce from mid2 (u32 col-pairs; 4 groups of 16 rows) ----
    {
        int cp2 = (tid & 63) * 2;
        int g = tid >> 6;       // 0..3
        int r0 = g * 16;
        float a0 = 0.f, a1 = 0.f;
        int cur = rowA[r0];
        for (int row = r0; row < r0 + 16; row++) {
            int rn = rowA[row];
            if (rn != cur) {
                atomicAdd(&m_i[(size_t)cur * 128 + cp2], a0);
                atomicAdd(&m_i[(size_t)cur * 128 + cp2 + 1], a1);
                a0 = 0.f; a1 = 0.f;
                cur = rn;
            }
            unsigned int v = *(const unsigned int*)&mid2[row * 132 + cp2];
            a0 += u2f(v << 16);
            a1 += u2f(v & 0xffff0000u);
        }
        atomicAdd(&m_i[(size_t)cur * 128 + cp2], a0);
        atomicAdd(&m_i[(size_t)cur * 128 + cp2 + 1], a1);
    }

    // ---- coord epilogue: fs = tanh(c1 . wc2) * 0.1
    {
        float part[4][4];
#pragma unroll
        for (int et = 0; et < 4; et++)
#pragma unroll
            for (int r = 0; r < 4; r++) part[et][r] = 0.f;
#pragma unroll
        for (int nt = 0; nt < 2; nt++) {
            int col = nbase + nt * 16 + ln15;
            float bias = bc1[col];
            float w2 = wc2[col];
#pragma unroll
            for (int et = 0; et < 4; et++)
#pragma unroll
                for (int r = 0; r < 4; r++)
                    part[et][r] += silu(acc[et][nt][r] + bias) * w2;
        }
#pragma unroll
        for (int et = 0; et < 4; et++)
#pragma unroll
            for (int r = 0; r < 4; r++) {
                float p = part[et][r];
                p += __shfl_xor(p, 8, 16);
                p += __shfl_xor(p, 4, 16);
                p += __shfl_xor(p, 2, 16);
                p += __shfl_xor(p, 1, 16);
                if (ln15 == 0) atomicAdd(&fsum[et * 16 + q4 + r], p);
            }
    }
    __syncthreads();
    if (tid < 64) {
        float fs = tanhf(fsum[tid]) * 0.1f;
        ndx[tid] *= fs; ndy[tid] *= fs; ndz[tid] *= fs;
    }
    __syncthreads();
    if (tid < 64) {
        bool head = (tid == 0) || (rowA[tid] != rowA[tid - 1]);
        if (head) {
            int rn = rowA[tid];
            float ax = 0.f, ay = 0.f, az = 0.f;
            for (int j = tid; j < 64 && rowA[j] == rn; j++) {
                ax += ndx[j]; ay += ndy[j]; az += ndz[j];
            }
            atomicAdd(&x_acc[rn * 3 + 0], ax);
            atomicAdd(&x_acc[rn * 3 + 1], ay);
            atomicAdd(&x_acc[rn * 3 + 2], az);
        }
    }
}

// ---- node kernel: 64 nodes per block + fused x update ----
__global__ __launch_bounds__(256, 4) void node_kernel(
    const float* __restrict__ h, const float* __restrict__ m_i,
    const float* __restrict__ x, const float* __restrict__ x_acc,
    const unsigned short* __restrict__ Wn1T, const float* __restrict__ bn1,
    const unsigned short* __restrict__ Wn2T, const float* __restrict__ bn2,
    const float* __restrict__ ln_g, const float* __restrict__ ln_b,
    float* __restrict__ out_h, float* __restrict__ out_x) {
    __shared__ unsigned short Alds[64 * 264];
    unsigned short* mid1 = Alds;
    float* tile = (float*)Alds;

    const int tid = threadIdx.x;
    const int n0 = blockIdx.x * 64;

    if (tid < 192) {
        int i = n0 * 3 + tid;
        if (i < NN * 3) out_x[i] = x[i] + x_acc[i];
    }

    // stage A = [bf16(h) | bf16(m_i)]
#pragma unroll
    for (int i = 0; i < 8; i++) {
        int idx = tid + i * 256;
        int hr = idx >> 4, ch = idx & 15;
        int e = hr >> 1, half = hr & 1;
        int node = n0 + e;
        if (node >= NN) node = NN - 1;
        const float* src = half ? &m_i[(size_t)node * 128 + ch * 8]
                                : &h[(size_t)node * 128 + ch * 8];
        const f32x4* sp = (const f32x4*)src;
        f32x4 f0 = sp[0], f1 = sp[1];
        u32x4 s;
        s[0] = f2bf_pk(f0[0], f0[1]);
        s[1] = f2bf_pk(f0[2], f0[3]);
        s[2] = f2bf_pk(f1[0], f1[1]);
        s[3] = f2bf_pk(f1[2], f1[3]);
        *(u32x4*)&Alds[e * 264 + half * 128 + ch * 8] = s;
    }
    __syncthreads();

    const int lane = tid & 63;
    const int w = tid >> 6;
    const int ln15 = lane & 15;
    const int q8 = (lane >> 4) * 8, q4 = (lane >> 4) * 4;
    const int nbase = w * 32;

    f32x4 acc[4][2];

    // ---- layer n1: K=256
#pragma unroll
    for (int et = 0; et < 4; et++)
#pragma unroll
        for (int nt = 0; nt < 2; nt++) acc[et][nt] = (f32x4){0.f, 0.f, 0.f, 0.f};
#pragma unroll
    for (int kk = 0; kk < 8; kk++) {
        int k0 = kk * 32 + q8;
        s16x8 a[4], b[2];
#pragma unroll
        for (int et = 0; et < 4; et++)
            a[et] = *(const s16x8*)&Alds[(et * 16 + ln15) * 264 + k0];
#pragma unroll
        for (int nt = 0; nt < 2; nt++)
            b[nt] = *(const s16x8*)&Wn1T[(nbase + nt * 16 + ln15) * 256 + k0];
#pragma unroll
        for (int et = 0; et < 4; et++)
#pragma unroll
            for (int nt = 0; nt < 2; nt++)
                acc[et][nt] = __builtin_amdgcn_mfma_f32_16x16x32_bf16(
                    a[et], b[nt], acc[et][nt], 0, 0, 0);
    }
    __syncthreads();  // A dead; mid1 overwrites
#pragma unroll
    for (int nt = 0; nt < 2; nt++) {
        int col = nbase + nt * 16 + ln15;
        float bias = bn1[col];
#pragma unroll
        for (int et = 0; et < 4; et++)
#pragma unroll
            for (int r = 0; r < 4; r++) {
                int row = et * 16 + q4 + r;
                mid1[row * 132 + col] = f2bf(silu(acc[et][nt][r] + bias));
            }
    }
    __syncthreads();

    // ---- layer n2: K=128
#pragma unroll
    for (int et = 0; et < 4; et++)
#pragma unroll
        for (int nt = 0; nt < 2; nt++) acc[et][nt] = (f32x4){0.f, 0.f, 0.f, 0.f};
#pragma unroll
    for (int kk = 0; kk < 4; kk++) {
        int k0 = kk * 32 + q8;
        s16x8 a[4], b[2];
#pragma unroll
        for (int et = 0; et < 4; et++)
            a[et] = *(const s16x8*)&mid1[(et * 16 + ln15) * 132 + k0];
#pragma unroll
        for (int nt = 0; nt < 2; nt++)
            b[nt] = *(const s16x8*)&Wn2T[(nbase + nt * 16 + ln15) * 128 + k0];
#pragma unroll
        for (int et = 0; et < 4; et++)
#pragma unroll
            for (int nt = 0; nt < 2; nt++)
                acc[et][nt] = __builtin_amdgcn_mfma_f32_16x16x32_bf16(
                    a[et], b[nt], acc[et][nt], 0, 0, 0);
    }
    __syncthreads();  // mid1 dead; f32 tile overwrites
#pragma unroll
    for (int nt = 0; nt < 2; nt++) {
        int col = nbase + nt * 16 + ln15;
        float bias = bn2[col];
#pragma unroll
        for (int et = 0; et < 4; et++)
#pragma unroll
            for (int r = 0; r < 4; r++) {
                int row = et * 16 + q4 + r;
                int node = n0 + row;
                int nclamp = node >= NN ? NN - 1 : node;
                float v = acc[et][nt][r] + bias + h[(size_t)nclamp * 128 + col];
                tile[row * 132 + col] = v;
            }
    }
    __syncthreads();

    // ---- LayerNorm: 4 threads/row, interleaved cols
    {
        int row = tid >> 2;
        int q = tid & 3;
        float s = 0.f, s2 = 0.f;
#pragma unroll
        for (int c = 0; c < 32; c++) {
            float v = tile[row * 132 + q + c * 4];
            s += v; s2 += v * v;
        }
        s += __shfl_xor(s, 1, 4);  s2 += __shfl_xor(s2, 1, 4);
        s += __shfl_xor(s, 2, 4);  s2 += __shfl_xor(s2, 2, 4);
        float mean = s * (1.f / 128.f);
        float var = s2 * (1.f / 128.f) - mean * mean;
        float rs = rsqrtf(var + 1e-5f);
        int node = n0 + row;
        if (node < NN) {
#pragma unroll
            for (int c = 0; c < 32; c++) {
                int col = q + c * 4;
                float v = (tile[row * 132 + col] - mean) * rs * ln_g[col] + ln_b[col];
                out_h[(size_t)node * 128 + col] = v;
            }
        }
    }
}

extern "C" void kernel_launch(void* const* d_in, const int* in_sizes, int n_in,
                              void* d_out, int out_size, void* d_ws, size_t ws_size,
                              hipStream_t stream) {
    const float* h    = (const float*)d_in[0];
    const float* x    = (const float*)d_in[1];
    const int* eidx   = (const int*)d_in[2];
    const float* W_e1 = (const float*)d_in[3];
    const float* b_e1 = (const float*)d_in[4];
    const float* W_e2 = (const float*)d_in[5];
    const float* b_e2 = (const float*)d_in[6];
    const float* W_c1 = (const float*)d_in[7];
    const float* b_c1 = (const float*)d_in[8];
    const float* W_c2 = (const float*)d_in[9];
    const float* W_n1 = (const float*)d_in[10];
    const float* b_n1 = (const float*)d_in[11];
    const float* W_n2 = (const float*)d_in[12];
    const float* b_n2 = (const float*)d_in[13];
    const float* ln_g = (const float*)d_in[14];
    const float* ln_b = (const float*)d_in[15];

    float* out_h = (float*)d_out;
    float* out_x = out_h + NN * HH;

    char* ws = (char*)d_ws;
    float* m_i    = (float*)ws;                       // 25,600,000 (zero)
    float* x_acc  = (float*)(ws + 25600000);          //    600,000 (zero)
    int* counts   = (int*)(ws + 26200000);            //    200,000 (zero)
    int* cursor   = (int*)(ws + 26400000);            //    200,000 (zero)
    int* offsets  = (int*)(ws + 26600000);            //    200,000
    int* partials = (int*)(ws + 26800000);            //      1,024
    int* scanp    = (int*)(ws + 26801024);            //      1,024
    unsigned int* rc = (unsigned int*)(ws + 26802048);       //  3,200,000
    float* P1 = (float*)(ws + 30002048);                     // 25,600,000
    float* P2 = (float*)(ws + 55602048);                     // 25,600,000
    unsigned short* PWT  = (unsigned short*)(ws + 81202048); //     65,536
    unsigned short* W2T  = (unsigned short*)(ws + 81267584); //     32,768
    unsigned short* Wc1T = (unsigned short*)(ws + 81300352); //     32,768
    unsigned short* Wn1T = (unsigned short*)(ws + 81333120); //     65,536
    unsigned short* Wn2T = (unsigned short*)(ws + 81398656); //     32,768

    hipMemsetAsync(ws, 0, 26800000, stream);  // m_i + x_acc + counts + cursor

    prep_kernel<<<(114688 + NE + 255) / 256, 256, 0, stream>>>(
        W_e1, W_e2, W_c1, W_n1, W_n2, eidx, PWT, W2T, Wc1T, Wn1T, Wn2T, counts);
    k_partial<<<SCAN_NB, 256, 0, stream>>>(counts, partials);
    k_scanp<<<1, 256, 0, stream>>>(partials, scanp);
    k_offsets<<<SCAN_NB, 256, 0, stream>>>(counts, scanp, offsets);
    k_fill<<<(NE + 255) / 256, 256, 0, stream>>>(eidx, offsets, cursor, rc);
    pgemm<<<(NN + 63) / 64, 256, 0, stream>>>(h, PWT, b_e1, P1, P2);

    edge_kernel<<<NE / 64, 256, 0, stream>>>(P1, P2, x, rc, W_e1, W2T, b_e2,
                                             Wc1T, b_c1, W_c2, m_i, x_acc);
    node_kernel<<<(NN + 63) / 64, 256, 0, stream>>>(
        h, m_i, x, x_acc, Wn1T, b_n1, Wn2T, b_n2, ln_g, ln_b, out_h, out_x);
}